// Round 8
// baseline (186.346 us; speedup 1.0000x reference)
//
#include <hip/hip_runtime.h>

// S4D real: y[l,c] = sum_s w[c,s] * h_s[l],  h_s[l] = x[l,c] + r[c,s]*h_s[l-1]
//
// R13: ONE kernel, two TREE barriers. Evidence chain:
//  - R12 (best, 90.7us): fill ~42 + 3 kernels+gaps ~48, vs ~11-15us work floor
//    -> ~8-10us per dispatch node of gap/drain/ramp. Dispatch count is the lever.
//  - R9 fused kernel did ALL work in ~19us busy time; its 510us overhead was
//    the barrier: 1024 pollers on ONE cacheline at s_sleep(2) (~19 loads/ns).
//  - Fix: tree barrier. 8 shard counters on SEPARATE 128B lines (64 arrivals
//    each, one RMW per block), shard-last promotes to root; pollers read root
//    with s_sleep(16) backoff (~0.43us interval -> ~1.2 reads/ns aggregate).
//  - Residency proof: 512 blocks, __launch_bounds__(256,2), LDS 9KB -> 2
//    blocks/CU -> ALL co-resident -> every block reaches every barrier.
//  - Bounded spin (~90ms/barrier): logic bug => wrong answer, never a hang.
//  - rocprof replay without the memset: counters stale/poisoned >= target ->
//    barriers no-op -> garbage only in that profiling pass, no hang.
// Phase bodies are VERBATIM the passing R12 kernels:
//  A: k_local (prefetched chunk scan, T=64) -> chunk-end states E
//  B: k_comb  (4 waves x 16 chunks, LDS group prefix) -> carry-ins in place
//  C: k_scan  (prefetched seeded re-scan + LDS cross-wave y reduce)

namespace {

constexpr int L_ = 4096;
constexpr int CH_ = 512;
constexpr int S_ = 64;
constexpr float DT = 1.0f / 4096.0f;
constexpr int SC = S_ * CH_;   // 32768 (s,c) pairs
constexpr int SG = 16;         // states per thread (S_ / 4 waves)
constexpr int T_ = 64;         // chunk length
constexpr int NC_ = L_ / T_;   // 64 chunks
constexpr int GJ = 16;         // chunks per combine thread (4 waves x 16 = 64)
constexpr int NB = NC_ * 8;    // 512 blocks

// counters: shard s of phase p at ctr[(p*16+s)*32], root of phase p at
// ctr[(p*16+8)*32]  (each on its own 128B line). 2 phases -> 25*32 u32s.
constexpr int CTR_U32 = 25 * 32;

__device__ __forceinline__ void tree_barrier(unsigned* __restrict__ ctr,
                                             int phase, int shard) {
  unsigned* sh = ctr + (phase * 16 + shard) * 32;
  unsigned* rt = ctr + (phase * 16 + 8) * 32;
  __syncthreads();
  if (threadIdx.x == 0) {
    __threadfence();  // publish this block's global writes
    const unsigned t = __hip_atomic_fetch_add(sh, 1u, __ATOMIC_ACQ_REL,
                                              __HIP_MEMORY_SCOPE_AGENT);
    if (t == 63u)  // shard-last of 64 arrivals
      __hip_atomic_fetch_add(rt, 1u, __ATOMIC_ACQ_REL,
                             __HIP_MEMORY_SCOPE_AGENT);
    // Bounded poll with backoff (~90ms max): wrong answer beats a hang.
    for (int it = 0; it < 200000; ++it) {
      if (__hip_atomic_load(rt, __ATOMIC_ACQUIRE,
                            __HIP_MEMORY_SCOPE_AGENT) >= 8u)
        break;
      __builtin_amdgcn_s_sleep(16);  // ~1024 cyc between polls
    }
    __threadfence();  // import other blocks' writes
  }
  __syncthreads();
}

// Compute r (and optionally w) for states [s0, s0+16) of channel c.
__device__ __forceinline__ void params16(const float* __restrict__ la,
                                         const float* __restrict__ Bg,
                                         const float* __restrict__ Cg,
                                         int c, int s0, float* r, float* w) {
  const float4* lap = reinterpret_cast<const float4*>(la + c * S_ + s0);
  if (w == nullptr) {
#pragma unroll
    for (int q = 0; q < 4; ++q) {
      const float4 v = lap[q];
      const float a[4] = {v.x, v.y, v.z, v.w};
#pragma unroll
      for (int t = 0; t < 4; ++t) {
        const float A = -expf(a[t]);
        r[q * 4 + t] = expf(A * DT);
      }
    }
  } else {
    const float4* bp = reinterpret_cast<const float4*>(Bg + c * S_ + s0);
    const float4* cp = reinterpret_cast<const float4*>(Cg + c * S_ + s0);
#pragma unroll
    for (int q = 0; q < 4; ++q) {
      const float4 v = lap[q], bb = bp[q], cc = cp[q];
      const float a[4] = {v.x, v.y, v.z, v.w};
      const float bv[4] = {bb.x, bb.y, bb.z, bb.w};
      const float cv[4] = {cc.x, cc.y, cc.z, cc.w};
#pragma unroll
      for (int t = 0; t < 4; ++t) {
        const float A = -expf(a[t]);
        const float rr = expf(A * DT);
        r[q * 4 + t] = rr;
        w[q * 4 + t] = cv[t] * ((rr - 1.0f) * bv[t] / A);
      }
    }
  }
}

// ---------------------------------------------------------------------------
__global__ __launch_bounds__(256, 2)
void s4d_one(const float* __restrict__ x, const float* __restrict__ la,
             const float* __restrict__ Bg, const float* __restrict__ Cg,
             float* __restrict__ carry,   // [NC_][SC] = 8 MB
             unsigned* __restrict__ ctr,  // barrier counters (memset to 0)
             float* __restrict__ y) {
  __shared__ float lds[4][8][64];  // phase C reduce (8 KB)
  __shared__ float aggs[4][64];    // phase B group prefix (1 KB)

  const int tid = threadIdx.x;
  const int bid = blockIdx.x;
  const int lane = tid & 63;
  const int g = tid >> 6;          // wave id
  const int k = bid >> 3;          // chunk
  const int cb = (bid & 7) << 6;   // channel-block base
  const int c = cb + lane;
  const int s0 = g * SG;

  // ---------------- Phase A: local chunk scan -> chunk-end states -----------
  {
    const float* xp = x + (size_t)k * T_ * CH_ + c;
    float xb[16];
#pragma unroll
    for (int j = 0; j < 16; ++j) xb[j] = xp[j * CH_];  // issue before expf

    float r[SG], h[SG];
    params16(la, nullptr, nullptr, c, s0, r, nullptr);
#pragma unroll
    for (int i = 0; i < SG; ++i) h[i] = 0.0f;

    for (int l0 = 0; l0 < T_; l0 += 16) {
      float xc[16];
#pragma unroll
      for (int j = 0; j < 16; ++j) xc[j] = xb[j];
      const int ln = (l0 + 16 < T_) ? l0 + 16 : l0;  // branchless tail
#pragma unroll
      for (int j = 0; j < 16; ++j) xb[j] = xp[(ln + j) * CH_];
#pragma unroll
      for (int j = 0; j < 16; ++j) {
        const float xv = xc[j];
#pragma unroll
        for (int i = 0; i < SG; ++i) h[i] = fmaf(r[i], h[i], xv);
      }
    }

    float* ew = carry + (size_t)k * SC + s0 * CH_ + c;
#pragma unroll
    for (int i = 0; i < SG; ++i) ew[i * CH_] = h[i];
  }

  tree_barrier(ctr, 0, bid & 7);

  // ---------------- Phase B: chunk ends -> chunk carry-ins (in place) -------
  // Re-identity: block = 64 pids x 4 waves; wave j owns chunks [16j, 16j+16).
  {
    const int p = tid & 63;
    const int j = g;                        // 0..3, wave-uniform
    const int pid = (bid << 6) + p;         // s*CH + c
    const int s = pid >> 9;
    const int c2 = pid & (CH_ - 1);

    float v[GJ];
#pragma unroll
    for (int m = 0; m < GJ; ++m) v[m] = carry[(size_t)(j * GJ + m) * SC + pid];

    const float A = -expf(la[c2 * S_ + s]);
    const float rT = expf(A * (DT * (float)T_));  // r^T
    float rTG = rT;                                // -> rT^16 (4 squarings)
    rTG *= rTG; rTG *= rTG; rTG *= rTG; rTG *= rTG;

    float agg = 0.0f;
#pragma unroll
    for (int m = 0; m < GJ; ++m) agg = fmaf(rT, agg, v[m]);
    aggs[j][p] = agg;
    __syncthreads();

    float G = 0.0f;  // carry-in of group j
    for (int j2 = 0; j2 < j; ++j2) G = fmaf(rTG, G, aggs[j2][p]);

    float st = G;
#pragma unroll
    for (int m = 0; m < GJ; ++m) {
      carry[(size_t)(j * GJ + m) * SC + pid] = st;  // carry-IN of chunk
      st = fmaf(rT, st, v[m]);
    }
  }

  tree_barrier(ctr, 1, bid & 7);

  // ---------------- Phase C: seeded re-scan + output ------------------------
  {
    float h[SG];
    const float* crd = carry + (size_t)k * SC + s0 * CH_ + c;
#pragma unroll
    for (int i = 0; i < SG; ++i) h[i] = crd[i * CH_];  // issue early

    const float* xp = x + (size_t)k * T_ * CH_ + c;
    float xb[8];
#pragma unroll
    for (int j = 0; j < 8; ++j) xb[j] = xp[j * CH_];   // issue early

    float r[SG], w[SG];
    params16(la, Bg, Cg, c, s0, r, w);

    float* yp = y + (size_t)k * T_ * CH_;

    for (int l = 0; l < T_; l += 8) {
      float xc[8];
#pragma unroll
      for (int j = 0; j < 8; ++j) xc[j] = xb[j];
      const int ln = (l + 8 < T_) ? l + 8 : l;  // branchless tail
#pragma unroll
      for (int j = 0; j < 8; ++j) xb[j] = xp[(ln + j) * CH_];

      float part[8];
#pragma unroll
      for (int jj = 0; jj < 8; ++jj) {
        const float xv = xc[jj];
        float a0 = 0, a1 = 0, a2 = 0, a3 = 0;
#pragma unroll
        for (int i = 0; i < SG; i += 4) {
          h[i]     = fmaf(r[i],     h[i],     xv);
          h[i + 1] = fmaf(r[i + 1], h[i + 1], xv);
          h[i + 2] = fmaf(r[i + 2], h[i + 2], xv);
          h[i + 3] = fmaf(r[i + 3], h[i + 3], xv);
          a0 = fmaf(w[i],     h[i],     a0);
          a1 = fmaf(w[i + 1], h[i + 1], a1);
          a2 = fmaf(w[i + 2], h[i + 2], a2);
          a3 = fmaf(w[i + 3], h[i + 3], a3);
        }
        part[jj] = (a0 + a1) + (a2 + a3);
      }

#pragma unroll
      for (int jj = 0; jj < 8; ++jj) lds[g][jj][lane] = part[jj];
      __syncthreads();
#pragma unroll
      for (int p = 0; p < 2; ++p) {
        const int idx = tid + p * 256;
        const int jj = idx >> 6;
        const int ln2 = idx & 63;
        const float vv = (lds[0][jj][ln2] + lds[1][jj][ln2]) +
                         (lds[2][jj][ln2] + lds[3][jj][ln2]);
        yp[(size_t)(l + jj) * CH_ + cb + ln2] = vv;
      }
      __syncthreads();
    }
  }
}

// ---------------- Degenerate fallback: full-length serial scan --------------
__global__ __launch_bounds__(256) void k_scan_full(const float* __restrict__ x,
                                                   const float* __restrict__ la,
                                                   const float* __restrict__ Bg,
                                                   const float* __restrict__ Cg,
                                                   float* __restrict__ y) {
  __shared__ float lds[4][8][64];
  const int lane = threadIdx.x & 63;
  const int g = threadIdx.x >> 6;
  const int cb = (blockIdx.x & 7) << 6;
  const int c = cb + lane;
  const int s0 = g * SG;

  float r[SG], w[SG], h[SG];
  params16(la, Bg, Cg, c, s0, r, w);
#pragma unroll
  for (int i = 0; i < SG; ++i) h[i] = 0.0f;

  const float* xp = x + c;
  float* yp = y;

  for (int l = 0; l < L_; l += 8) {
    float part[8];
#pragma unroll
    for (int jj = 0; jj < 8; ++jj) {
      const float xv = xp[(size_t)(l + jj) * CH_];
      float a0 = 0, a1 = 0, a2 = 0, a3 = 0;
#pragma unroll
      for (int i = 0; i < SG; i += 4) {
        h[i]     = fmaf(r[i],     h[i],     xv);
        h[i + 1] = fmaf(r[i + 1], h[i + 1], xv);
        h[i + 2] = fmaf(r[i + 2], h[i + 2], xv);
        h[i + 3] = fmaf(r[i + 3], h[i + 3], xv);
        a0 = fmaf(w[i],     h[i],     a0);
        a1 = fmaf(w[i + 1], h[i + 1], a1);
        a2 = fmaf(w[i + 2], h[i + 2], a2);
        a3 = fmaf(w[i + 3], h[i + 3], a3);
      }
      part[jj] = (a0 + a1) + (a2 + a3);
    }
#pragma unroll
    for (int jj = 0; jj < 8; ++jj) lds[g][jj][lane] = part[jj];
    __syncthreads();
#pragma unroll
    for (int p = 0; p < 2; ++p) {
      const int idx = (int)threadIdx.x + p * 256;
      const int jj = idx >> 6;
      const int ln = idx & 63;
      const float vv = (lds[0][jj][ln] + lds[1][jj][ln]) +
                       (lds[2][jj][ln] + lds[3][jj][ln]);
      yp[(size_t)(l + jj) * CH_ + cb + ln] = vv;
    }
    __syncthreads();
  }
}

}  // namespace

extern "C" void kernel_launch(void* const* d_in, const int* in_sizes, int n_in,
                              void* d_out, int out_size, void* d_ws, size_t ws_size,
                              hipStream_t stream) {
  const float* x = (const float*)d_in[0];
  const float* la = (const float*)d_in[1];
  const float* B = (const float*)d_in[2];
  const float* C = (const float*)d_in[3];
  float* y = (float*)d_out;
  float* ws = (float*)d_ws;

  const size_t carry_f = (size_t)NC_ * SC;  // 8 MB
  const size_t need = carry_f * sizeof(float) + CTR_U32 * sizeof(unsigned);
  if (ws_size >= need) {
    float* carry = ws;
    unsigned* ctr = (unsigned*)(ws + carry_f);
    hipMemsetAsync((void*)ctr, 0, CTR_U32 * sizeof(unsigned), stream);
    s4d_one<<<NB, 256, 0, stream>>>(x, la, B, C, carry, ctr, y);
  } else {
    k_scan_full<<<8, 256, 0, stream>>>(x, la, B, C, y);
  }
}